// Round 1
// baseline (175.577 us; speedup 1.0000x reference)
//
#include <hip/hip_runtime.h>

#define NP      4096
#define WINDOW  327
#define HALF    163
#define RL      20
#define NA      262144
#define GN_EPS  1e-6f

// fast tanh: tanh(x) = 1 - 2/(e^{2x}+1).  exp->inf => 1, exp->0 => -1. ~1e-7 abs err.
__device__ __forceinline__ float tanh_fast(float x) {
  float e = __expf(2.0f * x);
  return 1.0f - 2.0f / (e + 1.0f);
}

__device__ __forceinline__ float wave_sum64(float v) {
#pragma unroll
  for (int m = 1; m < 64; m <<= 1) v += __shfl_xor(v, m, 64);
  return v;
}

// ---------------- Kernel 1: per-start (4096 rows) branch net -> hc table ----------------
// One wave handles ROWS=4 consecutive starts; each lane owns 4 features (f = 4*lane..4*lane+3).
// GN stats via in-register shfl_xor butterflies. LDS h-buffer stride 260 (float4-aligned,
// rows land on distinct banks for the broadcast reads).
#define ROWS 4
#define SETS 4
#define HSTR 260
#define SETF 1536   // 332 (espan) + 160 (obsT) + 1040 (hbuf) padded

__global__ __launch_bounds__(256) void dc_precompute(
    const float* __restrict__ zc, const float* __restrict__ zt,
    const float* __restrict__ bW0, const float* __restrict__ bb0,
    const float* __restrict__ bs0, const float* __restrict__ bB0,
    const float* __restrict__ bW1, const float* __restrict__ bb1,
    const float* __restrict__ bs1, const float* __restrict__ bB1,
    const float* __restrict__ cW,  const float* __restrict__ cb,
    float* __restrict__ hc)
{
  __shared__ float smem[SETS * SETF];
  const int tid  = threadIdx.x;
  const int set  = tid >> 6;
  const int lane = tid & 63;
  const int s0   = blockIdx.x * (ROWS * SETS) + set * ROWS;

  float* espan = smem + set * SETF;   // [330] error window span for 4 rows
  float* obsT  = espan + 332;         // [40][4] observation, transposed (k-major)
  float* hbuf  = obsT + 160;          // [4][HSTR] hidden activations

  // Phase A: error span (edge-clamped == jnp.pad 'edge')
  for (int t = lane; t < WINDOW + ROWS - 1; t += 64) {
    int c = s0 - HALF + t;
    c = c < 0 ? 0 : (c > NP - 1 ? NP - 1 : c);
    espan[t] = zc[c] - zt[c];
  }
  __syncthreads();

  // Phase B: jax.image.resize(bilinear, antialias) of err and gradient -> obs[40] per row.
  // weights: triangle(|x-j|/16.35), renormalized over valid j (matches JAX edge renorm).
  {
    const float INV  = (float)WINDOW / (float)RL;   // 16.35
    const float RINV = (float)RL / (float)WINDOW;
    for (int task = lane; task < ROWS * 2 * RL; task += 64) {
      int q = task % (2 * RL);
      int r = task / (2 * RL);
      int qq = (q < RL) ? q : q - RL;
      float xs = ((float)qq + 0.5f) * INV - 0.5f;
      int jlo = (int)ceilf(xs - INV);  if (jlo < 0) jlo = 0;
      int jhi = (int)floorf(xs + INV); if (jhi > WINDOW - 1) jhi = WINDOW - 1;
      const float* p = espan + r;
      float wsum = 0.0f, acc = 0.0f;
      for (int j = jlo; j <= jhi; ++j) {
        float w = 1.0f - fabsf(xs - (float)j) * RINV;
        float v;
        if (q < RL) {
          v = p[j];
        } else {  // jnp.gradient: fwd/bwd diff at edges, central inside
          v = (j == 0) ? (p[1] - p[0]) :
              (j == WINDOW - 1) ? (p[WINDOW - 1] - p[WINDOW - 2]) :
              0.5f * (p[j + 1] - p[j - 1]);
        }
        wsum += w;
        acc  += w * v;
      }
      obsT[q * 4 + r] = acc / wsum;
    }
  }
  __syncthreads();

  // Phase C: layer0 (40 -> 256), 4 rows x 4 features per lane
  float acc0[ROWS][4];
  {
    float4 b = ((const float4*)bb0)[lane];
#pragma unroll
    for (int r = 0; r < ROWS; ++r) { acc0[r][0]=b.x; acc0[r][1]=b.y; acc0[r][2]=b.z; acc0[r][3]=b.w; }
    for (int k = 0; k < 2 * RL; ++k) {
      float4 ov = *(const float4*)&obsT[4 * k];             // rows 0..3 at k (LDS broadcast)
      float4 wv = ((const float4*)bW0)[k * 64 + lane];      // bW0[k*256 + 4*lane]
      float o[4] = {ov.x, ov.y, ov.z, ov.w};
      float w[4] = {wv.x, wv.y, wv.z, wv.w};
#pragma unroll
      for (int r = 0; r < ROWS; ++r)
#pragma unroll
        for (int j = 0; j < 4; ++j) acc0[r][j] = fmaf(o[r], w[j], acc0[r][j]);
    }
  }

  // Phase D: GroupNorm(1) + tanh, write h0 to LDS
  {
    float4 sc = ((const float4*)bs0)[lane];
    float4 bi = ((const float4*)bB0)[lane];
    float scl[4] = {sc.x, sc.y, sc.z, sc.w};
    float bia[4] = {bi.x, bi.y, bi.z, bi.w};
#pragma unroll
    for (int r = 0; r < ROWS; ++r) {
      float s = acc0[r][0] + acc0[r][1] + acc0[r][2] + acc0[r][3];
      s = wave_sum64(s);
      float mu = s * (1.0f / 256.0f);
      float d[4], ss = 0.0f;
#pragma unroll
      for (int j = 0; j < 4; ++j) { d[j] = acc0[r][j] - mu; ss += d[j] * d[j]; }
      ss = wave_sum64(ss);
      float rv = rsqrtf(ss * (1.0f / 256.0f) + GN_EPS);
      float4 hv;
      hv.x = tanh_fast(d[0] * rv * scl[0] + bia[0]);
      hv.y = tanh_fast(d[1] * rv * scl[1] + bia[1]);
      hv.z = tanh_fast(d[2] * rv * scl[2] + bia[2]);
      hv.w = tanh_fast(d[3] * rv * scl[3] + bia[3]);
      *(float4*)&hbuf[r * HSTR + 4 * lane] = hv;
    }
  }
  __syncthreads();

  // Phase E: layer1 (256 -> 256)
  float acc1[ROWS][4];
  {
    float4 b = ((const float4*)bb1)[lane];
#pragma unroll
    for (int r = 0; r < ROWS; ++r) { acc1[r][0]=b.x; acc1[r][1]=b.y; acc1[r][2]=b.z; acc1[r][3]=b.w; }
    for (int kk = 0; kk < 256; kk += 4) {
      float hk[ROWS][4];
#pragma unroll
      for (int r = 0; r < ROWS; ++r) {
        float4 hv = *(const float4*)&hbuf[r * HSTR + kk];   // broadcast b128
        hk[r][0]=hv.x; hk[r][1]=hv.y; hk[r][2]=hv.z; hk[r][3]=hv.w;
      }
#pragma unroll
      for (int i = 0; i < 4; ++i) {
        float4 wv = ((const float4*)bW1)[(kk + i) * 64 + lane];
        float w[4] = {wv.x, wv.y, wv.z, wv.w};
#pragma unroll
        for (int r = 0; r < ROWS; ++r)
#pragma unroll
          for (int j = 0; j < 4; ++j) acc1[r][j] = fmaf(hk[r][i], w[j], acc1[r][j]);
      }
    }
  }

  // Phase F: GN + tanh -> h1 back into hbuf (same wave owns buffer; in-wave LDS order is safe)
  {
    float4 sc = ((const float4*)bs1)[lane];
    float4 bi = ((const float4*)bB1)[lane];
    float scl[4] = {sc.x, sc.y, sc.z, sc.w};
    float bia[4] = {bi.x, bi.y, bi.z, bi.w};
#pragma unroll
    for (int r = 0; r < ROWS; ++r) {
      float s = acc1[r][0] + acc1[r][1] + acc1[r][2] + acc1[r][3];
      s = wave_sum64(s);
      float mu = s * (1.0f / 256.0f);
      float d[4], ss = 0.0f;
#pragma unroll
      for (int j = 0; j < 4; ++j) { d[j] = acc1[r][j] - mu; ss += d[j] * d[j]; }
      ss = wave_sum64(ss);
      float rv = rsqrtf(ss * (1.0f / 256.0f) + GN_EPS);
      float4 hv;
      hv.x = tanh_fast(d[0] * rv * scl[0] + bia[0]);
      hv.y = tanh_fast(d[1] * rv * scl[1] + bia[1]);
      hv.z = tanh_fast(d[2] * rv * scl[2] + bia[2]);
      hv.w = tanh_fast(d[3] * rv * scl[3] + bia[3]);
      *(float4*)&hbuf[r * HSTR + 4 * lane] = hv;
    }
  }
  __syncthreads();

  // Phase G: hc[row][f] = cb[f] + h1 . cW_top[:,f]   (rows 0..255 of cW)
  for (int task = lane; task < ROWS * 32; task += 64) {
    int r = task >> 5;
    int f = task & 31;
    float acc = cb[f];
    for (int kk = 0; kk < 256; kk += 4) {
      float4 hv = *(const float4*)&hbuf[r * HSTR + kk];
      acc = fmaf(hv.x, cW[(kk    ) * 32 + f], acc);
      acc = fmaf(hv.y, cW[(kk + 1) * 32 + f], acc);
      acc = fmaf(hv.z, cW[(kk + 2) * 32 + f], acc);
      acc = fmaf(hv.w, cW[(kk + 3) * 32 + f], acc);
    }
    hc[(s0 + r) * 32 + f] = acc;
  }
}

// ---------------- Kernel 2: per-agent trunk + combine + heads ----------------
// All weight accesses use wave-uniform addresses (constant-index unrolled loops) so the
// compiler emits s_load_* -> SGPR broadcast; only xi, hc[s], and outputs are per-lane.
__global__ __launch_bounds__(256) void dc_agents(
    const float* __restrict__ xi_curr, const float* __restrict__ hc,
    const float* __restrict__ tW0, const float* __restrict__ tb0,
    const float* __restrict__ tW1, const float* __restrict__ tb1,
    const float* __restrict__ cW,
    const float* __restrict__ uW, const float* __restrict__ ub,
    const float* __restrict__ vW, const float* __restrict__ vb,
    float* __restrict__ out)
{
  const int a = blockIdx.x * 256 + threadIdx.x;
  float xi = xi_curr[a];
  int s = (int)(xi * 4095.0f);   // matches (xi*(N-1)).astype(int32)

  // Fourier features via angle-doubling: sin/cos of pi*xi*{1,2,4,8}
  float ang = xi * 3.14159265358979323846f;
  float s1 = __sinf(ang), c1 = __cosf(ang);
  float s2 = 2.0f * s1 * c1, c2 = 1.0f - 2.0f * s1 * s1;
  float s4 = 2.0f * s2 * c2, c4 = 1.0f - 2.0f * s2 * s2;
  float s8 = 2.0f * s4 * c4, c8 = 1.0f - 2.0f * s4 * s4;
  float enc[8] = {s1, s2, s4, s8, c1, c2, c4, c8};

  float t0[32];
#pragma unroll
  for (int f = 0; f < 32; ++f) t0[f] = tb0[f];
#pragma unroll
  for (int k = 0; k < 8; ++k) {
    float e = enc[k];
#pragma unroll
    for (int f = 0; f < 32; ++f) t0[f] = fmaf(e, tW0[k * 32 + f], t0[f]);
  }
#pragma unroll
  for (int f = 0; f < 32; ++f) t0[f] = tanh_fast(t0[f]);

  float t1[32];
#pragma unroll
  for (int f = 0; f < 32; ++f) t1[f] = tb1[f];
#pragma unroll
  for (int k = 0; k < 32; ++k) {
    float e = t0[k];
#pragma unroll
    for (int f = 0; f < 32; ++f) t1[f] = fmaf(e, tW1[k * 32 + f], t1[f]);
  }
#pragma unroll
  for (int f = 0; f < 32; ++f) t1[f] = tanh_fast(t1[f]);

  // combined: hc[s] (already includes h@cW_top + cb) + enc32 @ cW_bot (rows 256..287)
  float xv[32];
  const float4* hp = (const float4*)(hc + s * 32);
#pragma unroll
  for (int q = 0; q < 8; ++q) {
    float4 h4 = hp[q];
    xv[4 * q + 0] = h4.x; xv[4 * q + 1] = h4.y;
    xv[4 * q + 2] = h4.z; xv[4 * q + 3] = h4.w;
  }
#pragma unroll
  for (int k = 0; k < 32; ++k) {
    float e = t1[k];
#pragma unroll
    for (int f = 0; f < 32; ++f) xv[f] = fmaf(e, cW[(256 + k) * 32 + f], xv[f]);
  }
#pragma unroll
  for (int f = 0; f < 32; ++f) xv[f] = tanh_fast(xv[f]);

  float u = ub[0], v = vb[0];
#pragma unroll
  for (int k = 0; k < 32; ++k) {
    u = fmaf(xv[k], uW[k], u);
    v = fmaf(xv[k], vW[k], v);
  }
  out[a]      = 40.0f * tanh_fast(u);
  out[NA + a] = tanh_fast(v);
}

extern "C" void kernel_launch(void* const* d_in, const int* in_sizes, int n_in,
                              void* d_out, int out_size, void* d_ws, size_t ws_size,
                              hipStream_t stream) {
  const float* zc  = (const float*)d_in[0];
  const float* zt  = (const float*)d_in[1];
  const float* xi  = (const float*)d_in[2];
  const float* bW0 = (const float*)d_in[3];
  const float* bb0 = (const float*)d_in[4];
  const float* bs0 = (const float*)d_in[5];
  const float* bB0 = (const float*)d_in[6];
  const float* bW1 = (const float*)d_in[7];
  const float* bb1 = (const float*)d_in[8];
  const float* bs1 = (const float*)d_in[9];
  const float* bB1 = (const float*)d_in[10];
  const float* tW0 = (const float*)d_in[11];
  const float* tb0 = (const float*)d_in[12];
  const float* tW1 = (const float*)d_in[13];
  const float* tb1 = (const float*)d_in[14];
  const float* cW  = (const float*)d_in[15];
  const float* cb  = (const float*)d_in[16];
  const float* uW  = (const float*)d_in[17];
  const float* ub  = (const float*)d_in[18];
  const float* vW  = (const float*)d_in[19];
  const float* vb  = (const float*)d_in[20];

  float* hc  = (float*)d_ws;               // 4096 x 32 fp32 = 512 KB
  float* out = (float*)d_out;              // [u(262144), v(262144)]

  // 4096 starts / (4 rows * 4 sets) = 256 blocks
  dc_precompute<<<256, 256, 0, stream>>>(zc, zt, bW0, bb0, bs0, bB0,
                                         bW1, bb1, bs1, bB1, cW, cb, hc);
  dc_agents<<<NA / 256, 256, 0, stream>>>(xi, hc, tW0, tb0, tW1, tb1, cW,
                                          uW, ub, vW, vb, out);
}